// Round 4
// baseline (20004.549 us; speedup 1.0000x reference)
//
#include <hip/hip_runtime.h>

// Residual VQ — bit-faithful replication of the numpy-f32 reference.
// Key insight: ref=np computes dist = ||r||^2 - 2 r.c + ||c||^2 in FLOAT32,
// where the ||r||^2 (~256) term quantizes distances at ulp(256)=3e-5 ->
// hundreds of exact f32 ties resolved by np.argmin's first-index rule.
// We replicate the f32 arithmetic:
//   dot:  BLAS sgemm microkernel = sequential FMA chain over d ascending
//   A=||r||^2: any f32 works (per-row constant -> integer-ulp uniform shift
//              of the dist row -> argmin invariant); we use the same pairwise
//              pattern as C for safety.
//   C=||c||^2: numpy pairwise_sum, AVX512 dispatch flavor (4x16-lane accs
//              over 128-blocks, _mm512_reduce_add_ps tree).
//   combine:  fl(fl(A - fl(2*dot)) + C), argmin strict-<, ascending k.
//   residual: r = fl(r - c[idx]) elementwise (exact chain).
// All precision-critical ops use __fadd_rn/__fmul_rn/__fsub_rn/fmaf to block
// -ffp-contract=fast reassociation/fusion.

#define NTOK 131072
#define DEPTH 8
#define KCB 1024
#define DIM 256
#define TM 32   // tokens per block
#define TK 32   // codewords per chunk
#define RP 260  // padded LDS row length (floats)

// numpy FLOAT_pairwise_sum (AVX512 build) of the squares of 128 contiguous
// floats: 4 vector accumulators (16 lanes), 2 passes, lanewise combine
// (r0+r1)+(r2+r3), then _mm512_reduce_add_ps tree.
__device__ __forceinline__ float np_sumsq_128(const float* p) {
  float s[16];
#pragma unroll
  for (int l = 0; l < 16; ++l) {
    float r0 = __fadd_rn(__fmul_rn(p[l], p[l]),
                         __fmul_rn(p[l + 64], p[l + 64]));
    float r1 = __fadd_rn(__fmul_rn(p[l + 16], p[l + 16]),
                         __fmul_rn(p[l + 80], p[l + 80]));
    float r2 = __fadd_rn(__fmul_rn(p[l + 32], p[l + 32]),
                         __fmul_rn(p[l + 96], p[l + 96]));
    float r3 = __fadd_rn(__fmul_rn(p[l + 48], p[l + 48]),
                         __fmul_rn(p[l + 112], p[l + 112]));
    s[l] = __fadd_rn(__fadd_rn(r0, r1), __fadd_rn(r2, r3));
  }
  float t[8];
#pragma unroll
  for (int l = 0; l < 8; ++l) t[l] = __fadd_rn(s[l], s[l + 8]);
  float u[4];
#pragma unroll
  for (int l = 0; l < 4; ++l) u[l] = __fadd_rn(t[l], t[l + 4]);
  return __fadd_rn(__fadd_rn(u[0], u[2]), __fadd_rn(u[1], u[3]));
}

__device__ __forceinline__ float np_sumsq_256(const float* p) {
  // n=256 > PW_BLOCKSIZE=128 -> split in halves, add.
  return __fadd_rn(np_sumsq_128(p), np_sumsq_128(p + 128));
}

// Precompute C[lvl][k] = np-pattern sum(c^2) for all codewords.
__global__ __launch_bounds__(256) void c2_kernel(
    const float* __restrict__ cbs, float* __restrict__ C32g) {
  int gid = blockIdx.x * 256 + threadIdx.x;  // 0..8191
  C32g[gid] = np_sumsq_256(cbs + (size_t)gid * DIM);
}

__global__ __launch_bounds__(256, 1) void rvq_np_kernel(
    const float* __restrict__ latent, const float* __restrict__ cbs,
    const float* __restrict__ C32g, float* __restrict__ out) {
  __shared__ float r_m[TM][RP];   // residual, row-major, exact f32 chain
  __shared__ float c_m[TK][RP];   // staged codebook chunk, row-major
  __shared__ float Cl[KCB];       // np-exact ||c||^2 for this level
  __shared__ float A_s[TM];       // f32 ||r||^2 per token
  __shared__ int idx_s[TM];       // chosen codes this level

  const int tid = threadIdx.x;
  const int n0 = blockIdx.x * TM;
  const int trow = tid >> 4;  // 0..15, owns tokens 2*trow, 2*trow+1
  const int kcol = tid & 15;  // owns chunk k's 2*kcol, 2*kcol+1
  const int t0 = trow * 2, t1 = trow * 2 + 1;

  // ---- stage latent -> r_m (exact copy) ----
  {
    int tok = tid >> 3;
    int db = (tid & 7) * 32;
#pragma unroll
    for (int j = 0; j < 8; ++j) {
      float4 v = *(const float4*)(latent + (size_t)(n0 + tok) * DIM + db + j * 4);
      *(float4*)&r_m[tok][db + j * 4] = v;
    }
  }
  __syncthreads();

  for (int lvl = 0; lvl < DEPTH; ++lvl) {
    const float* cb = cbs + (size_t)lvl * KCB * DIM;
    if (tid < TM) A_s[tid] = np_sumsq_256(&r_m[tid][0]);
    for (int j = tid; j < KCB; j += 256) Cl[j] = C32g[lvl * KCB + j];
    __syncthreads();

    float best0 = 3.4e38f, best1 = 3.4e38f;
    int bi0 = 0, bi1 = 0;

    for (int chunk = 0; chunk < KCB / TK; ++chunk) {
      // ---- stage codebook chunk ----
      {
        int kk = tid >> 3;
        int db = (tid & 7) * 32;
        const float* src = cb + (size_t)(chunk * TK + kk) * DIM + db;
#pragma unroll
        for (int j = 0; j < 8; ++j)
          *(float4*)&c_m[kk][db + j * 4] = *(const float4*)(src + j * 4);
      }
      __syncthreads();

      // ---- dot: sequential FMA chain over d ascending (BLAS order) ----
      const int k0 = kcol * 2, k1 = kcol * 2 + 1;
      float a00 = 0.f, a01 = 0.f, a10 = 0.f, a11 = 0.f;
#pragma unroll 4
      for (int q = 0; q < 64; ++q) {
        float4 ra = *(const float4*)&r_m[t0][q * 4];
        float4 rb = *(const float4*)&r_m[t1][q * 4];
        float4 ca = *(const float4*)&c_m[k0][q * 4];
        float4 cc = *(const float4*)&c_m[k1][q * 4];
        a00 = fmaf(ra.x, ca.x, a00);
        a00 = fmaf(ra.y, ca.y, a00);
        a00 = fmaf(ra.z, ca.z, a00);
        a00 = fmaf(ra.w, ca.w, a00);
        a01 = fmaf(ra.x, cc.x, a01);
        a01 = fmaf(ra.y, cc.y, a01);
        a01 = fmaf(ra.z, cc.z, a01);
        a01 = fmaf(ra.w, cc.w, a01);
        a10 = fmaf(rb.x, ca.x, a10);
        a10 = fmaf(rb.y, ca.y, a10);
        a10 = fmaf(rb.z, ca.z, a10);
        a10 = fmaf(rb.w, ca.w, a10);
        a11 = fmaf(rb.x, cc.x, a11);
        a11 = fmaf(rb.y, cc.y, a11);
        a11 = fmaf(rb.z, cc.z, a11);
        a11 = fmaf(rb.w, cc.w, a11);
      }

      // ---- dist = fl(fl(A - fl(2*dot)) + C), merge ascending k ----
      int kg0 = chunk * TK + k0, kg1 = chunk * TK + k1;
      {
        float A0 = A_s[t0], A1 = A_s[t1];
        float C0 = Cl[kg0], C1 = Cl[kg1];
        float d00 = __fadd_rn(__fsub_rn(A0, __fmul_rn(2.0f, a00)), C0);
        float d01 = __fadd_rn(__fsub_rn(A0, __fmul_rn(2.0f, a01)), C1);
        float d10 = __fadd_rn(__fsub_rn(A1, __fmul_rn(2.0f, a10)), C0);
        float d11 = __fadd_rn(__fsub_rn(A1, __fmul_rn(2.0f, a11)), C1);
        if (d00 < best0) { best0 = d00; bi0 = kg0; }
        if (d01 < best0) { best0 = d01; bi0 = kg1; }
        if (d10 < best1) { best1 = d10; bi1 = kg0; }
        if (d11 < best1) { best1 = d11; bi1 = kg1; }
      }
      __syncthreads();  // scoring done before next chunk overwrites c_m
    }

    // ---- butterfly argmin over the 16 kcol lanes (first-index ties) ----
#pragma unroll
    for (int m = 1; m <= 8; m <<= 1) {
      float ob = __shfl_xor(best0, m);
      int oi = __shfl_xor(bi0, m);
      if (ob < best0 || (ob == best0 && oi < bi0)) { best0 = ob; bi0 = oi; }
      ob = __shfl_xor(best1, m);
      oi = __shfl_xor(bi1, m);
      if (ob < best1 || (ob == best1 && oi < bi1)) { best1 = ob; bi1 = oi; }
    }

    // ---- write codes + share indices ----
    if (kcol == 0) {
      out[(size_t)NTOK * DIM + (size_t)lvl * NTOK + n0 + t0] = (float)bi0;
      out[(size_t)NTOK * DIM + (size_t)lvl * NTOK + n0 + t1] = (float)bi1;
      idx_s[t0] = bi0;
      idx_s[t1] = bi1;
    }
    __syncthreads();

    // ---- residual update: r = fl(r - c[idx]) elementwise ----
    {
      int tok = tid >> 3;
      int db = (tid & 7) * 32;
      const float* crow = cb + (size_t)idx_s[tok] * DIM + db;
#pragma unroll
      for (int j = 0; j < 8; ++j) {
        float4 cv = *(const float4*)(crow + j * 4);
        int d = db + j * 4;
        r_m[tok][d + 0] = __fsub_rn(r_m[tok][d + 0], cv.x);
        r_m[tok][d + 1] = __fsub_rn(r_m[tok][d + 1], cv.y);
        r_m[tok][d + 2] = __fsub_rn(r_m[tok][d + 2], cv.z);
        r_m[tok][d + 3] = __fsub_rn(r_m[tok][d + 3], cv.w);
      }
    }
    __syncthreads();
  }

  // ---- straight_through = latent + (qsum - latent), qsum ~= latent - r ----
  {
    int tok = tid >> 3;
    int db = (tid & 7) * 32;
#pragma unroll
    for (int j = 0; j < 8; ++j) {
      int d = db + j * 4;
      size_t gi = (size_t)(n0 + tok) * DIM + d;
      float4 l4 = *(const float4*)(latent + gi);
      float4 qv;
      float q;
      q = __fsub_rn(l4.x, r_m[tok][d + 0]);
      qv.x = __fadd_rn(l4.x, __fsub_rn(q, l4.x));
      q = __fsub_rn(l4.y, r_m[tok][d + 1]);
      qv.y = __fadd_rn(l4.y, __fsub_rn(q, l4.y));
      q = __fsub_rn(l4.z, r_m[tok][d + 2]);
      qv.z = __fadd_rn(l4.z, __fsub_rn(q, l4.z));
      q = __fsub_rn(l4.w, r_m[tok][d + 3]);
      qv.w = __fadd_rn(l4.w, __fsub_rn(q, l4.w));
      *(float4*)(out + gi) = qv;
    }
  }
}

extern "C" void kernel_launch(void* const* d_in, const int* in_sizes, int n_in,
                              void* d_out, int out_size, void* d_ws,
                              size_t ws_size, hipStream_t stream) {
  const float* latent = (const float*)d_in[0];
  const float* codebooks = (const float*)d_in[1];
  float* out = (float*)d_out;
  float* C32g = (float*)d_ws;  // 8192 floats = 32 KB scratch

  hipLaunchKernelGGL(c2_kernel, dim3(DEPTH * KCB / 256), dim3(256), 0, stream,
                     codebooks, C32g);
  hipLaunchKernelGGL(rvq_np_kernel, dim3(NTOK / TM), dim3(256), 0, stream,
                     latent, codebooks, C32g, out);
}

// Round 6
// 10894.553 us; speedup vs baseline: 1.8362x; 1.8362x over previous
//
#include <hip/hip_runtime.h>

// Residual VQ — np-f32 bit-faithful, perf round (staging-count bugfix).
// Frozen numerics (validated round 4):
//   dot:   single sequential fmaf chain over d=0..255 ascending per (tok,k)
//   A,C:   np pairwise-sum-of-squares (AVX512 tree) replica
//   dist:  fl(fl(A - fl(2*dot)) + C), argmin strict-<, first-index ties
//   resid: r = fl(r - c[idx]) elementwise
//
// Org: block = 32 tokens, 512 threads = 8 waves. Wave w owns k in
// [128w, 128w+128). Lane grid 4 tg x 16 kg; per lane 8 tokens (tg+4i) x
// 8 k (128w+kg+16j), acc[8][8] persists over 16 d-slices of 16.
// LDS: r_m[32][260] row-major (4 concurrent rows -> distinct bank quads),
// c_s[1024*16] with float4-slot XOR swizzle part^((k>>1)&3) (2-way max).

#define NTOK 131072
#define DEPTH 8
#define KCB 1024
#define DIM 256
#define TM 32
#define DS 16
#define NSLICE (DIM / DS)
#define RP 260

__device__ __forceinline__ float np_sumsq_128(const float* p) {
  float s[16];
#pragma unroll
  for (int l = 0; l < 16; ++l) {
    float r0 = __fadd_rn(__fmul_rn(p[l], p[l]),
                         __fmul_rn(p[l + 64], p[l + 64]));
    float r1 = __fadd_rn(__fmul_rn(p[l + 16], p[l + 16]),
                         __fmul_rn(p[l + 80], p[l + 80]));
    float r2 = __fadd_rn(__fmul_rn(p[l + 32], p[l + 32]),
                         __fmul_rn(p[l + 96], p[l + 96]));
    float r3 = __fadd_rn(__fmul_rn(p[l + 48], p[l + 48]),
                         __fmul_rn(p[l + 112], p[l + 112]));
    s[l] = __fadd_rn(__fadd_rn(r0, r1), __fadd_rn(r2, r3));
  }
  float t[8];
#pragma unroll
  for (int l = 0; l < 8; ++l) t[l] = __fadd_rn(s[l], s[l + 8]);
  float u[4];
#pragma unroll
  for (int l = 0; l < 4; ++l) u[l] = __fadd_rn(t[l], t[l + 4]);
  return __fadd_rn(__fadd_rn(u[0], u[2]), __fadd_rn(u[1], u[3]));
}

__device__ __forceinline__ float np_sumsq_256(const float* p) {
  return __fadd_rn(np_sumsq_128(p), np_sumsq_128(p + 128));
}

__global__ __launch_bounds__(256) void c2_kernel(const float* __restrict__ cbs,
                                                 float* __restrict__ C32g) {
  int gid = blockIdx.x * 256 + threadIdx.x;
  C32g[gid] = np_sumsq_256(cbs + (size_t)gid * DIM);
}

__global__ __launch_bounds__(512, 1) void rvq_kernel(
    const float* __restrict__ latent, const float* __restrict__ cbs,
    const float* __restrict__ C32g, float* __restrict__ out) {
  __shared__ float r_m[TM][RP];
  __shared__ float c_s[KCB * DS];
  __shared__ float A_s[TM];
  __shared__ float best_s[8][TM];
  __shared__ int bidx_s[8][TM];
  __shared__ int idx_s[TM];

  const int tid = threadIdx.x;
  const int w = tid >> 6;
  const int lane = tid & 63;
  const int tg = lane >> 4;
  const int kg = lane & 15;
  const int n0 = blockIdx.x * TM;

  // ---- stage latent -> r_m (exact copy) ----
  {
    int tok = tid >> 4;
    int db = (tid & 15) * 16;
    const float* src = latent + (size_t)(n0 + tok) * DIM + db;
#pragma unroll
    for (int j = 0; j < 4; ++j)
      *(float4*)&r_m[tok][db + j * 4] = *(const float4*)(src + j * 4);
  }
  __syncthreads();

  const int kbase = w * 128 + kg;      // lane's k_j = kbase + 16*j
  const int swz = (kbase >> 1) & 3;    // j-independent (16j>>1 = 8j == 0 mod 4)

  for (int lvl = 0; lvl < DEPTH; ++lvl) {
    const float* cb = cbs + (size_t)lvl * KCB * DIM;
    if (tid < TM) A_s[tid] = np_sumsq_256(&r_m[tid][0]);

    float acc[8][8];
#pragma unroll
    for (int i = 0; i < 8; ++i)
#pragma unroll
      for (int j = 0; j < 8; ++j) acc[i][j] = 0.f;

    for (int ds = 0; ds < NSLICE; ++ds) {
      __syncthreads();  // prev slice reads done (and A_s ordered at ds=0)
      // ---- stage full c-slice [1024 k][16 d], swizzled float4 slots ----
      // 4096 float4 slots / 512 threads = 8 each.
      {
        const int d0 = ds * DS;
        const int part = tid & 3;
#pragma unroll
        for (int g = 0; g < 8; ++g) {
          int k = g * 128 + (tid >> 2);
          float4 v = *(const float4*)(cb + (size_t)k * DIM + d0 + part * 4);
          int p2 = part ^ ((k >> 1) & 3);
          *(float4*)&c_s[k * 16 + p2 * 4] = v;
        }
      }
      __syncthreads();

      // ---- 4 substeps of 4 d-values each; chain strictly d-ascending ----
#pragma unroll
      for (int sub = 0; sub < 4; ++sub) {
        float4 rv[8], cv[8];
        const int rd = ds * DS + sub * 4;
#pragma unroll
        for (int i = 0; i < 8; ++i)
          rv[i] = *(const float4*)&r_m[tg + 4 * i][rd];
        const int csub = ((sub ^ swz) << 2);
#pragma unroll
        for (int j = 0; j < 8; ++j)
          cv[j] = *(const float4*)&c_s[(kbase + 16 * j) * 16 + csub];
#pragma unroll
        for (int i = 0; i < 8; ++i)
#pragma unroll
          for (int j = 0; j < 8; ++j) {
            float a = acc[i][j];
            a = fmaf(rv[i].x, cv[j].x, a);
            a = fmaf(rv[i].y, cv[j].y, a);
            a = fmaf(rv[i].z, cv[j].z, a);
            a = fmaf(rv[i].w, cv[j].w, a);
            acc[i][j] = a;
          }
      }
    }

    // ---- dist combine + per-lane argmin (j ascending = k ascending) ----
    float bv[8];
    int bk[8];
#pragma unroll
    for (int i = 0; i < 8; ++i) {
      bv[i] = 3.4e38f;
      bk[i] = 0;
    }
#pragma unroll
    for (int j = 0; j < 8; ++j) {
      const int k = kbase + 16 * j;
      const float C = C32g[lvl * KCB + k];
#pragma unroll
      for (int i = 0; i < 8; ++i) {
        float d = __fadd_rn(
            __fsub_rn(A_s[tg + 4 * i], __fmul_rn(2.0f, acc[i][j])), C);
        if (d < bv[i]) {
          bv[i] = d;
          bk[i] = k;
        }
      }
    }

    // ---- butterfly over the 16 kg lanes (index tie-break) ----
#pragma unroll
    for (int m = 1; m <= 8; m <<= 1) {
#pragma unroll
      for (int i = 0; i < 8; ++i) {
        float ov = __shfl_xor(bv[i], m);
        int ok = __shfl_xor(bk[i], m);
        if (ov < bv[i] || (ov == bv[i] && ok < bk[i])) {
          bv[i] = ov;
          bk[i] = ok;
        }
      }
    }
    if (kg == 0) {
#pragma unroll
      for (int i = 0; i < 8; ++i) {
        best_s[w][tg + 4 * i] = bv[i];
        bidx_s[w][tg + 4 * i] = bk[i];
      }
    }
    __syncthreads();

    // ---- cross-wave merge (w ascending = k ascending; strict <) ----
    if (tid < TM) {
      float b = best_s[0][tid];
      int k = bidx_s[0][tid];
#pragma unroll
      for (int ww = 1; ww < 8; ++ww) {
        float ov = best_s[ww][tid];
        int ok = bidx_s[ww][tid];
        if (ov < b || (ov == b && ok < k)) {
          b = ov;
          k = ok;
        }
      }
      idx_s[tid] = k;
      out[(size_t)NTOK * DIM + (size_t)lvl * NTOK + n0 + tid] = (float)k;
    }
    __syncthreads();

    // ---- residual update: r = fl(r - c[idx]) elementwise ----
    {
      int tok = tid >> 4;
      int db = (tid & 15) * 16;
      const float* crow = cb + (size_t)idx_s[tok] * DIM + db;
#pragma unroll
      for (int j = 0; j < 4; ++j) {
        float4 cv4 = *(const float4*)(crow + j * 4);
        int d = db + j * 4;
        r_m[tok][d + 0] = __fsub_rn(r_m[tok][d + 0], cv4.x);
        r_m[tok][d + 1] = __fsub_rn(r_m[tok][d + 1], cv4.y);
        r_m[tok][d + 2] = __fsub_rn(r_m[tok][d + 2], cv4.z);
        r_m[tok][d + 3] = __fsub_rn(r_m[tok][d + 3], cv4.w);
      }
    }
    __syncthreads();  // r stable before next level's A
  }

  // ---- straight_through = fl(l + fl(q - l)), q = fl(l - r) ----
  {
    int tok = tid >> 4;
    int db = (tid & 15) * 16;
#pragma unroll
    for (int j = 0; j < 4; ++j) {
      int d = db + j * 4;
      size_t gi = (size_t)(n0 + tok) * DIM + d;
      float4 l4 = *(const float4*)(latent + gi);
      float4 qv;
      float q;
      q = __fsub_rn(l4.x, r_m[tok][d + 0]);
      qv.x = __fadd_rn(l4.x, __fsub_rn(q, l4.x));
      q = __fsub_rn(l4.y, r_m[tok][d + 1]);
      qv.y = __fadd_rn(l4.y, __fsub_rn(q, l4.y));
      q = __fsub_rn(l4.z, r_m[tok][d + 2]);
      qv.z = __fadd_rn(l4.z, __fsub_rn(q, l4.z));
      q = __fsub_rn(l4.w, r_m[tok][d + 3]);
      qv.w = __fadd_rn(l4.w, __fsub_rn(q, l4.w));
      *(float4*)(out + gi) = qv;
    }
  }
}

extern "C" void kernel_launch(void* const* d_in, const int* in_sizes, int n_in,
                              void* d_out, int out_size, void* d_ws,
                              size_t ws_size, hipStream_t stream) {
  const float* latent = (const float*)d_in[0];
  const float* codebooks = (const float*)d_in[1];
  float* out = (float*)d_out;
  float* C32g = (float*)d_ws;  // 8192 floats

  hipLaunchKernelGGL(c2_kernel, dim3(DEPTH * KCB / 256), dim3(256), 0, stream,
                     codebooks, C32g);
  hipLaunchKernelGGL(rvq_kernel, dim3(NTOK / TM), dim3(512), 0, stream, latent,
                     codebooks, C32g, out);
}